// Round 4
// baseline (286.479 us; speedup 1.0000x reference)
//
#include <hip/hip_runtime.h>
#include <hip/hip_bf16.h>

typedef __attribute__((ext_vector_type(8))) short short8;
typedef __attribute__((ext_vector_type(4))) float floatx4;

#define C_DIM 256
#define NCE_T_INV 14.285714285714286f

// ---------------------------------------------------------------------------
// Kernel 1: fused prep — zero the rs accumulators AND gather labels.
// ---------------------------------------------------------------------------
__global__ void prep_kernel(const int* __restrict__ seg,
                            const int* __restrict__ coords,
                            const int* __restrict__ crw,
                            const int* __restrict__ crh,
                            const int* __restrict__ crd,
                            int* __restrict__ lab,
                            float* __restrict__ rs, int rs_n,
                            int N, int H, int W, int D) {
    int idx = blockIdx.x * blockDim.x + threadIdx.x;
    if (idx < rs_n) rs[idx] = 0.0f;
    if (idx < N) {
        int c0 = coords[3 * idx + 0];
        int c1 = coords[3 * idx + 1];
        int c2 = coords[3 * idx + 2];
        int i0 = (c0 * H) / crw[0];
        int i1 = (c1 * W) / crh[0];
        int i2 = (c2 * D) / crd[0];
        lab[idx] = seg[(i0 * W + i1) * D + i2];
    }
}

// ---------------------------------------------------------------------------
// Kernel 2: L2-normalize rows of f (M x 256 fp32) -> bf16 bits in g.
// One wave per row, 4 rows per block.
// ---------------------------------------------------------------------------
__global__ void norm_kernel(const float* __restrict__ f,
                            unsigned short* __restrict__ g) {
    int row = blockIdx.x * 4 + (threadIdx.x >> 6);
    int lane = threadIdx.x & 63;
    const float4 v = ((const float4*)(f + (size_t)row * C_DIM))[lane];
    float ss = v.x * v.x + v.y * v.y + v.z * v.z + v.w * v.w;
#pragma unroll
    for (int off = 32; off; off >>= 1) ss += __shfl_xor(ss, off, 64);
    float inv = 1.0f / sqrtf(ss);

    ushort4 o;
    __hip_bfloat16 b0 = __float2bfloat16(v.x * inv);
    __hip_bfloat16 b1 = __float2bfloat16(v.y * inv);
    __hip_bfloat16 b2 = __float2bfloat16(v.z * inv);
    __hip_bfloat16 b3 = __float2bfloat16(v.w * inv);
    o.x = __builtin_bit_cast(unsigned short, b0);
    o.y = __builtin_bit_cast(unsigned short, b1);
    o.z = __builtin_bit_cast(unsigned short, b2);
    o.w = __builtin_bit_cast(unsigned short, b3);
    ((ushort4*)g)[(size_t)row * (C_DIM / 4) + lane] = o;
}

// ---------------------------------------------------------------------------
// Kernel 3: barrier-free symmetric Gram kernel.
// One WAVE = one independent 64x64 output tile of sim = G @ G^T, operands
// loaded directly global->VGPR (G is 4 MB, L2/L3-resident; no LDS, no
// __syncthreads anywhere). Triangular wave-tile grid over 128 row-blocks of
// 64: t -> (i,j), j <= i; 8256 wave-tiles = 2064 blocks x 4 waves.
// Each global_load_dwordx4 touches 16 fully-used 64B lines (cq spans the
// line), so no wasted bytes. Epilogue: shuffle row/col reductions +
// fire-and-forget global atomics (same as round 3, verified).
// ---------------------------------------------------------------------------
__global__ __launch_bounds__(256, 4) void
gram_kernel(const unsigned short* __restrict__ G,
            const int* __restrict__ lab,
            float* __restrict__ rs_exp,
            float* __restrict__ rs_num,
            float* __restrict__ rs_cnt,
            int labmask, int nt64) {
    const int wave = threadIdx.x >> 6;
    const int lane = threadIdx.x & 63;
    const int t = blockIdx.x * 4 + wave;
    const int T = nt64 * (nt64 + 1) / 2;
    if (t >= T) return;

    // decode triangular index: i = row-block, j = col-block, j <= i
    int i = (int)((sqrtf(8.0f * (float)t + 1.0f) - 1.0f) * 0.5f);
    while ((i + 1) * (i + 2) / 2 <= t) ++i;
    while (i * (i + 1) / 2 > t) --i;
    const int j = t - i * (i + 1) / 2;

    const int cc = lane & 15;
    const int cq = lane >> 4;
    const int rowA0 = i * 64;
    const int rowB0 = j * 64;
    const bool diagTile = (i == j);

    const unsigned short* GA = G + ((size_t)rowA0 << 8);  // row stride 256
    const unsigned short* GB = G + ((size_t)rowB0 << 8);

    floatx4 acc[4][4] = {};

#pragma unroll
    for (int ks = 0; ks < 8; ++ks) {  // K = 8 * 32 = 256
        short8 af[4], bf[4];
#pragma unroll
        for (int mi = 0; mi < 4; ++mi)
            af[mi] = *(const short8*)(GA + ((size_t)(mi * 16 + cc) << 8) + ks * 32 + cq * 8);
#pragma unroll
        for (int ni = 0; ni < 4; ++ni)
            bf[ni] = *(const short8*)(GB + ((size_t)(ni * 16 + cc) << 8) + ks * 32 + cq * 8);
#pragma unroll
        for (int mi = 0; mi < 4; ++mi)
#pragma unroll
            for (int ni = 0; ni < 4; ++ni)
                acc[mi][ni] = __builtin_amdgcn_mfma_f32_16x16x32_bf16(
                    af[mi], bf[ni], acc[mi][ni], 0, 0, 0);
    }

    // ---- epilogue ----
    int col_lab[4];
#pragma unroll
    for (int ni = 0; ni < 4; ++ni)
        col_lab[ni] = lab[(rowB0 + ni * 16 + cc) & labmask];

    float bse[4] = {}, bnu[4] = {}, bct[4] = {};

#pragma unroll
    for (int mi = 0; mi < 4; ++mi) {
#pragma unroll
        for (int r = 0; r < 4; ++r) {
            const int grow = rowA0 + mi * 16 + cq * 4 + r;
            const int rl = lab[grow & labmask];
            float se = 0.0f, nu = 0.0f, ct = 0.0f;
#pragma unroll
            for (int ni = 0; ni < 4; ++ni) {
                const int gcol = rowB0 + ni * 16 + cc;
                const float ls = (acc[mi][ni][r] - 1.0f) * NCE_T_INV;
                const bool valid = (gcol != grow);
                const float e = valid ? __expf(ls) : 0.0f;
                const bool pos = valid && (col_lab[ni] == rl);
                const float nuv = pos ? ls : 0.0f;
                const float p = pos ? 1.0f : 0.0f;
                se += e; nu += nuv; ct += p;
                bse[ni] += e; bnu[ni] += nuv; bct[ni] += p;
            }
            // reduce across the 16 cc lanes (columns of the tile)
#pragma unroll
            for (int off = 1; off < 16; off <<= 1) {
                se += __shfl_xor(se, off, 64);
                nu += __shfl_xor(nu, off, 64);
                ct += __shfl_xor(ct, off, 64);
            }
            if (cc == 0) {
                atomicAdd(&rs_exp[grow], se);
                atomicAdd(&rs_num[grow], nu);
                atomicAdd(&rs_cnt[grow], ct);
            }
        }
    }

    // ---- mirrored (column-side) contributions for off-diagonal tiles ----
    if (!diagTile) {
#pragma unroll
        for (int ni = 0; ni < 4; ++ni) {
            float se = bse[ni], nu = bnu[ni], ct = bct[ni];
            se += __shfl_xor(se, 16, 64); nu += __shfl_xor(nu, 16, 64); ct += __shfl_xor(ct, 16, 64);
            se += __shfl_xor(se, 32, 64); nu += __shfl_xor(nu, 32, 64); ct += __shfl_xor(ct, 32, 64);
            if (cq == 0) {
                const int gcol = rowB0 + ni * 16 + cc;
                atomicAdd(&rs_exp[gcol], se);
                atomicAdd(&rs_num[gcol], nu);
                atomicAdd(&rs_cnt[gcol], ct);
            }
        }
    }
}

// ---------------------------------------------------------------------------
// Kernel 4: finalize. loss = -mean_i( num_i/cnt_i - log(exp_i) )
// ---------------------------------------------------------------------------
__global__ void finalize_kernel(const float* __restrict__ rs_exp,
                                const float* __restrict__ rs_num,
                                const float* __restrict__ rs_cnt,
                                float* __restrict__ out, int M) {
    __shared__ float red[256];
    float s = 0.0f;
    for (int i = threadIdx.x; i < M; i += 256)
        s += rs_num[i] / rs_cnt[i] - logf(rs_exp[i]);
    red[threadIdx.x] = s;
    __syncthreads();
    for (int k = 128; k; k >>= 1) {
        if (threadIdx.x < k) red[threadIdx.x] += red[threadIdx.x + k];
        __syncthreads();
    }
    if (threadIdx.x == 0) out[0] = -red[0] / (float)M;
}

extern "C" void kernel_launch(void* const* d_in, const int* in_sizes, int n_in,
                              void* d_out, int out_size, void* d_ws, size_t ws_size,
                              hipStream_t stream) {
    const float* features = (const float*)d_in[0];
    const int* labels_seg = (const int*)d_in[1];
    const int* labels_coords = (const int*)d_in[2];
    const int* crw = (const int*)d_in[3];
    const int* crh = (const int*)d_in[4];
    const int* crd = (const int*)d_in[5];
    float* out = (float*)d_out;

    const int N = in_sizes[2] / 3;        // 4096 patches
    const int M = in_sizes[0] / C_DIM;    // 8192 rows
    const int H = 128, W = 128, D = 128;
    const int nt64 = M / 64;              // 128 tile-rows
    const int T = nt64 * (nt64 + 1) / 2;  // 8256 wave-tiles
    const int nblocks = (T + 3) / 4;      // 2064

    // workspace layout
    char* ws = (char*)d_ws;
    unsigned short* g = (unsigned short*)ws;                       // M*256 bf16 (4 MB)
    char* p1 = ws + (size_t)M * C_DIM * 2;
    int* lab = (int*)p1;                                           // N ints
    char* p2 = p1 + (size_t)N * 4;
    float* rs = (float*)p2;                                        // 3*M f32
    float* rs_exp = rs;
    float* rs_num = rs + M;
    float* rs_cnt = rs + 2 * M;

    prep_kernel<<<(3 * M + 255) / 256, 256, 0, stream>>>(
        labels_seg, labels_coords, crw, crh, crd, lab, rs, 3 * M, N, H, W, D);

    norm_kernel<<<M / 4, 256, 0, stream>>>(features, g);

    gram_kernel<<<nblocks, 256, 0, stream>>>(g, lab, rs_exp, rs_num, rs_cnt,
                                             N - 1, nt64);

    finalize_kernel<<<1, 256, 0, stream>>>(rs_exp, rs_num, rs_cnt, out, M);
}

// Round 5
// 238.057 us; speedup vs baseline: 1.2034x; 1.2034x over previous
//
#include <hip/hip_runtime.h>
#include <hip/hip_bf16.h>

typedef __attribute__((ext_vector_type(8))) short short8;
typedef __attribute__((ext_vector_type(4))) float floatx4;

#define C_DIM 256
#define NCE_T_INV 14.285714285714286f

// ---------------------------------------------------------------------------
// Kernel 1: gather downsampled labels.
// ---------------------------------------------------------------------------
__global__ void labels_kernel(const int* __restrict__ seg,
                              const int* __restrict__ coords,
                              const int* __restrict__ crw,
                              const int* __restrict__ crh,
                              const int* __restrict__ crd,
                              int* __restrict__ lab, int N, int H, int W, int D) {
    int p = blockIdx.x * blockDim.x + threadIdx.x;
    if (p >= N) return;
    int c0 = coords[3 * p + 0];
    int c1 = coords[3 * p + 1];
    int c2 = coords[3 * p + 2];
    int i0 = (c0 * H) / crw[0];
    int i1 = (c1 * W) / crh[0];
    int i2 = (c2 * D) / crd[0];
    lab[p] = seg[(i0 * W + i1) * D + i2];
}

// ---------------------------------------------------------------------------
// Kernel 2: L2-normalize rows of f (M x 256 fp32) -> bf16 bits in g.
// One wave per row, 4 rows per block.
// ---------------------------------------------------------------------------
__global__ void norm_kernel(const float* __restrict__ f,
                            unsigned short* __restrict__ g) {
    int row = blockIdx.x * 4 + (threadIdx.x >> 6);
    int lane = threadIdx.x & 63;
    const float4 v = ((const float4*)(f + (size_t)row * C_DIM))[lane];
    float ss = v.x * v.x + v.y * v.y + v.z * v.z + v.w * v.w;
#pragma unroll
    for (int off = 32; off; off >>= 1) ss += __shfl_xor(ss, off, 64);
    float inv = 1.0f / sqrtf(ss);

    ushort4 o;
    __hip_bfloat16 b0 = __float2bfloat16(v.x * inv);
    __hip_bfloat16 b1 = __float2bfloat16(v.y * inv);
    __hip_bfloat16 b2 = __float2bfloat16(v.z * inv);
    __hip_bfloat16 b3 = __float2bfloat16(v.w * inv);
    o.x = __builtin_bit_cast(unsigned short, b0);
    o.y = __builtin_bit_cast(unsigned short, b1);
    o.z = __builtin_bit_cast(unsigned short, b2);
    o.w = __builtin_bit_cast(unsigned short, b3);
    ((ushort4*)g)[(size_t)row * (C_DIM / 4) + lane] = o;
}

// ---------------------------------------------------------------------------
// Kernel 3: symmetric Gram-tile kernel, R3 compute structure, ATOMIC-FREE
// epilogue. Triangular 1D grid over 64 row-blocks of 128 (2080 blocks).
// K-loop: VGPR-staged LDS tiles, BK=64, pad to 72 shorts (stride 36 dw ==
// 4 mod 32 -> free 2-way ds_read_b128; measured 2.1e6 conflicts in R3).
// Epilogue: shuffle reductions -> LDS red[][][][] (union with tiles) ->
// one barrier -> coalesced exactly-once stores into part[slot][3][M]:
//   A-side of (tm,tn) -> slot tn, rows of tm;
//   B-side (off-diag)  -> slot tm, rows of tn.
// Row-block m receives slots {m..63} (A) and {0..m-1} (B): all 64 exactly
// once across the grid. No atomics anywhere.
// ---------------------------------------------------------------------------
struct Smem {
    union {
        unsigned short tiles[2][128][72];   // 36.9 KB
        float red[2][2][128][3];            // [A/B][wave-pair][row][cnt] 12 KB
    };
};

__global__ __launch_bounds__(256, 4) void
gram_kernel(const unsigned short* __restrict__ G,
            const int* __restrict__ lab,
            float* __restrict__ part,
            int M, int labmask, int nt) {
    // ---- decode triangular block index (wave-uniform) ----
    const int b = blockIdx.x;
    float fnt = (float)nt;
    float disc = (2.0f * fnt + 1.0f) * (2.0f * fnt + 1.0f) - 8.0f * (float)b;
    int tm = (int)((2.0f * fnt + 1.0f - sqrtf(disc)) * 0.5f);
    if (tm < 0) tm = 0;
    if (tm > nt - 1) tm = nt - 1;
    while (tm > 0 && b < tm * nt - tm * (tm - 1) / 2) --tm;
    while (b >= (tm + 1) * nt - (tm + 1) * tm / 2) ++tm;
    const int tn = tm + (b - (tm * nt - tm * (tm - 1) / 2));

    __shared__ Smem sm;

    const int tid = threadIdx.x;
    const int lane = tid & 63;
    const int wave = tid >> 6;
    const int waveM = wave >> 1;
    const int waveN = wave & 1;
    const int cc = lane & 15;
    const int cq = lane >> 4;
    const int rowA0 = tm * 128;
    const int rowB0 = tn * 128;
    const bool diagTile = (tm == tn);

    floatx4 acc[4][4];
#pragma unroll
    for (int mi = 0; mi < 4; ++mi)
#pragma unroll
        for (int ni = 0; ni < 4; ++ni)
            acc[mi][ni] = floatx4{-1.0f, -1.0f, -1.0f, -1.0f};  // folds (sim-1)

    for (int kk = 0; kk < C_DIM; kk += 64) {
#pragma unroll
        for (int t = 0; t < 8; ++t) {
            const int vi = t * 256 + tid;
            const int row = (vi >> 3) & 127;
            const int cv = vi & 7;
            const uint4 val =
                *(const uint4*)&G[(size_t)((t < 4 ? rowA0 : rowB0) + row) * C_DIM + kk + cv * 8];
            if (t < 4) *(uint4*)&sm.tiles[0][row][cv * 8] = val;
            else       *(uint4*)&sm.tiles[1][row][cv * 8] = val;
        }
        __syncthreads();

#pragma unroll
        for (int ks = 0; ks < 64; ks += 32) {
            short8 af[4], bf[4];
#pragma unroll
            for (int mi = 0; mi < 4; ++mi)
                af[mi] = *(const short8*)&sm.tiles[0][waveM * 64 + mi * 16 + cc][ks + cq * 8];
#pragma unroll
            for (int ni = 0; ni < 4; ++ni)
                bf[ni] = *(const short8*)&sm.tiles[1][waveN * 64 + ni * 16 + cc][ks + cq * 8];
#pragma unroll
            for (int mi = 0; mi < 4; ++mi)
#pragma unroll
                for (int ni = 0; ni < 4; ++ni)
                    acc[mi][ni] = __builtin_amdgcn_mfma_f32_16x16x32_bf16(
                        af[mi], bf[ni], acc[mi][ni], 0, 0, 0);
        }
        __syncthreads();
    }
    // after the final barrier all LDS reads are complete; tiles reusable.

    // ---- epilogue: shuffle-reduce, park in LDS, exactly-once stores ----
    int col_lab[4];
#pragma unroll
    for (int ni = 0; ni < 4; ++ni)
        col_lab[ni] = lab[(rowB0 + waveN * 64 + ni * 16 + cc) & labmask];

    float bse[4] = {}, bnu[4] = {}, bct[4] = {};

#pragma unroll
    for (int mi = 0; mi < 4; ++mi) {
#pragma unroll
        for (int r = 0; r < 4; ++r) {
            const int lrow = waveM * 64 + mi * 16 + cq * 4 + r;
            const int grow = rowA0 + lrow;
            const int rl = lab[grow & labmask];
            float se = 0.0f, nu = 0.0f, ct = 0.0f;
#pragma unroll
            for (int ni = 0; ni < 4; ++ni) {
                const int gcol = rowB0 + waveN * 64 + ni * 16 + cc;
                const float ls = acc[mi][ni][r] * NCE_T_INV;   // acc = sim-1
                const bool valid = (gcol != grow);
                const float e = valid ? __expf(ls) : 0.0f;
                const bool pos = valid && (col_lab[ni] == rl);
                const float nuv = pos ? ls : 0.0f;
                const float p = pos ? 1.0f : 0.0f;
                se += e; nu += nuv; ct += p;
                bse[ni] += e; bnu[ni] += nuv; bct[ni] += p;
            }
#pragma unroll
            for (int off = 1; off < 16; off <<= 1) {
                se += __shfl_xor(se, off, 64);
                nu += __shfl_xor(nu, off, 64);
                ct += __shfl_xor(ct, off, 64);
            }
            if (cc == 0) {              // lanes 0,16,32,48: one per cq
                sm.red[0][waveN][lrow][0] = se;
                sm.red[0][waveN][lrow][1] = nu;
                sm.red[0][waveN][lrow][2] = ct;
            }
        }
    }

    if (!diagTile) {
#pragma unroll
        for (int ni = 0; ni < 4; ++ni) {
            float se = bse[ni], nu = bnu[ni], ct = bct[ni];
            se += __shfl_xor(se, 16, 64); nu += __shfl_xor(nu, 16, 64); ct += __shfl_xor(ct, 16, 64);
            se += __shfl_xor(se, 32, 64); nu += __shfl_xor(nu, 32, 64); ct += __shfl_xor(ct, 32, 64);
            if (cq == 0) {              // 16 lanes: one per column cc
                const int lcol = waveN * 64 + ni * 16 + cc;
                sm.red[1][waveM][lcol][0] = se;
                sm.red[1][waveM][lcol][1] = nu;
                sm.red[1][waveM][lcol][2] = ct;
            }
        }
    }
    __syncthreads();

    // A-side partials -> slot tn, rows of tile tm (coalesced, exactly once)
    for (int v = tid; v < 384; v += 256) {
        const int c = v >> 7, r = v & 127;
        part[((size_t)(tn * 3 + c)) * M + rowA0 + r] =
            sm.red[0][0][r][c] + sm.red[0][1][r][c];
    }
    // B-side partials -> slot tm, rows of tile tn
    if (!diagTile) {
        for (int v = tid; v < 384; v += 256) {
            const int c = v >> 7, r = v & 127;
            part[((size_t)(tm * 3 + c)) * M + rowB0 + r] =
                sm.red[1][0][r][c] + sm.red[1][1][r][c];
        }
    }
}

// ---------------------------------------------------------------------------
// Kernel 4: per-row term = nu/ct - log(se), reducing over the 64 slots.
// part layout [slot][3][M] -> fully coalesced reads.
// ---------------------------------------------------------------------------
__global__ void rowterm_kernel(const float* __restrict__ part,
                               float* __restrict__ terms, int M, int nslots) {
    const int row = blockIdx.x * 256 + threadIdx.x;
    if (row >= M) return;
    float se = 0.0f, nu = 0.0f, ct = 0.0f;
    for (int s = 0; s < nslots; ++s) {
        const float* p = part + (size_t)s * 3 * M;
        se += p[row];
        nu += p[M + row];
        ct += p[2 * M + row];
    }
    terms[row] = nu / ct - logf(se);
}

// ---------------------------------------------------------------------------
// Kernel 5: final mean.
// ---------------------------------------------------------------------------
__global__ void reduce_kernel(const float* __restrict__ terms,
                              float* __restrict__ out, int M) {
    __shared__ float red[256];
    float s = 0.0f;
    for (int i = threadIdx.x; i < M; i += 256) s += terms[i];
    red[threadIdx.x] = s;
    __syncthreads();
    for (int k = 128; k; k >>= 1) {
        if (threadIdx.x < k) red[threadIdx.x] += red[threadIdx.x + k];
        __syncthreads();
    }
    if (threadIdx.x == 0) out[0] = -red[0] / (float)M;
}

extern "C" void kernel_launch(void* const* d_in, const int* in_sizes, int n_in,
                              void* d_out, int out_size, void* d_ws, size_t ws_size,
                              hipStream_t stream) {
    const float* features = (const float*)d_in[0];
    const int* labels_seg = (const int*)d_in[1];
    const int* labels_coords = (const int*)d_in[2];
    const int* crw = (const int*)d_in[3];
    const int* crh = (const int*)d_in[4];
    const int* crd = (const int*)d_in[5];
    float* out = (float*)d_out;

    const int N = in_sizes[2] / 3;          // 4096 patches
    const int M = in_sizes[0] / C_DIM;      // 8192 rows
    const int H = 128, W = 128, D = 128;
    const int nt = M / 128;                 // 64 row-blocks
    const int nblocks = nt * (nt + 1) / 2;  // 2080

    // workspace layout
    char* ws = (char*)d_ws;
    unsigned short* g = (unsigned short*)ws;                 // M*256 bf16 (4 MB)
    char* p1 = ws + (size_t)M * C_DIM * 2;
    int* lab = (int*)p1;                                     // N ints
    char* p2 = p1 + (size_t)N * 4;
    float* part = (float*)p2;                                // nt*3*M f32 (6.3 MB)
    char* p3 = p2 + (size_t)nt * 3 * M * 4;
    float* terms = (float*)p3;                               // M f32

    labels_kernel<<<(N + 255) / 256, 256, 0, stream>>>(
        labels_seg, labels_coords, crw, crh, crd, lab, N, H, W, D);

    norm_kernel<<<M / 4, 256, 0, stream>>>(features, g);

    gram_kernel<<<nblocks, 256, 0, stream>>>(g, lab, part, M, N - 1, nt);

    rowterm_kernel<<<(M + 255) / 256, 256, 0, stream>>>(part, terms, M, nt);

    reduce_kernel<<<1, 256, 0, stream>>>(terms, out, M);
}

// Round 6
// 206.461 us; speedup vs baseline: 1.3876x; 1.1530x over previous
//
#include <hip/hip_runtime.h>
#include <hip/hip_bf16.h>

typedef __attribute__((ext_vector_type(8))) short short8;
typedef __attribute__((ext_vector_type(4))) float floatx4;

#define C_DIM 256
// (1/T) * log2(e) : logits scaled to base-2 so exp2f -> v_exp_f32 directly.
#define K2_SCALE 20.60992915f
#define LN2F 0.6931471805599453f

// ---------------------------------------------------------------------------
// Kernel 1: gather downsampled labels.
// ---------------------------------------------------------------------------
__global__ void labels_kernel(const int* __restrict__ seg,
                              const int* __restrict__ coords,
                              const int* __restrict__ crw,
                              const int* __restrict__ crh,
                              const int* __restrict__ crd,
                              int* __restrict__ lab, int N, int H, int W, int D) {
    int p = blockIdx.x * blockDim.x + threadIdx.x;
    if (p >= N) return;
    int c0 = coords[3 * p + 0];
    int c1 = coords[3 * p + 1];
    int c2 = coords[3 * p + 2];
    int i0 = (c0 * H) / crw[0];
    int i1 = (c1 * W) / crh[0];
    int i2 = (c2 * D) / crd[0];
    lab[p] = seg[(i0 * W + i1) * D + i2];
}

// ---------------------------------------------------------------------------
// Kernel 2: L2-normalize rows of f (M x 256 fp32) -> bf16 in MFMA-tiled
// layout g2: element (row,k) lives at
//   panel = (row>>4)*8 + (k>>5)
//   off   = panel*512 + ((k>>3)&3)*128 + (row&15)*8 + (k&7)
// so an MFMA fragment (16 rows x 32 k) is 64 lanes x 8 contiguous shorts ->
// one fully-coalesced 1KB global_load_dwordx4 per fragment.
// One wave per row; lane l holds k = 4l..4l+3 -> one 8B short4 store.
// ---------------------------------------------------------------------------
__global__ void norm_kernel(const float* __restrict__ f,
                            unsigned short* __restrict__ g2) {
    int row = blockIdx.x * 4 + (threadIdx.x >> 6);
    int l = threadIdx.x & 63;
    const float4 v = ((const float4*)(f + (size_t)row * C_DIM))[l];
    float ss = v.x * v.x + v.y * v.y + v.z * v.z + v.w * v.w;
#pragma unroll
    for (int off = 32; off; off >>= 1) ss += __shfl_xor(ss, off, 64);
    float inv = 1.0f / sqrtf(ss);

    ushort4 o;
    __hip_bfloat16 b0 = __float2bfloat16(v.x * inv);
    __hip_bfloat16 b1 = __float2bfloat16(v.y * inv);
    __hip_bfloat16 b2 = __float2bfloat16(v.z * inv);
    __hip_bfloat16 b3 = __float2bfloat16(v.w * inv);
    o.x = __builtin_bit_cast(unsigned short, b0);
    o.y = __builtin_bit_cast(unsigned short, b1);
    o.z = __builtin_bit_cast(unsigned short, b2);
    o.w = __builtin_bit_cast(unsigned short, b3);

    // k = 4l: c32 = l>>3, cq = (l>>1)&3, k&7 = 4*(l&1)
    size_t off2 = ((size_t)(row >> 4) * 8 + (l >> 3)) * 512 +
                  ((size_t)((l >> 1) & 3)) * 128 + (size_t)(row & 15) * 8 +
                  (l & 1) * 4;
    *(ushort4*)(g2 + off2) = o;
}

// ---------------------------------------------------------------------------
// Kernel 3: symmetric Gram-tile kernel — barrier-free K-loop.
// Triangular 1D grid over 64 row-blocks of 128 (2080 blocks, R5 decode).
// 4 waves in 2x2; each wave's MFMA operands are loaded DIRECTLY from the
// tiled g2 (one coalesced dwordx4 per fragment, L2-resident, no LDS, no
// __syncthreads in the K-loop -> compiler pipelines loads across MFMAs).
// Epilogue (R5-proven): shuffle reduce -> park in 12KB LDS -> one barrier ->
// coalesced exactly-once stores into part[slot][3][M].
// ---------------------------------------------------------------------------
__global__ __launch_bounds__(256, 4) void
gram_kernel(const unsigned short* __restrict__ G2,
            const int* __restrict__ lab,
            float* __restrict__ part,
            int M, int labmask, int nt) {
    // ---- decode triangular block index (wave-uniform) ----
    const int b = blockIdx.x;
    float fnt = (float)nt;
    float disc = (2.0f * fnt + 1.0f) * (2.0f * fnt + 1.0f) - 8.0f * (float)b;
    int tm = (int)((2.0f * fnt + 1.0f - sqrtf(disc)) * 0.5f);
    if (tm < 0) tm = 0;
    if (tm > nt - 1) tm = nt - 1;
    while (tm > 0 && b < tm * nt - tm * (tm - 1) / 2) --tm;
    while (b >= (tm + 1) * nt - (tm + 1) * tm / 2) ++tm;
    const int tn = tm + (b - (tm * nt - tm * (tm - 1) / 2));

    __shared__ float red[2][2][128][3];   // 12.3 KB, epilogue only

    const int tid = threadIdx.x;
    const int lane = tid & 63;
    const int wave = tid >> 6;
    const int waveM = wave >> 1;
    const int waveN = wave & 1;
    const int cc = lane & 15;
    const int cq = lane >> 4;
    const int rowA0 = tm * 128;
    const int rowB0 = tn * 128;
    const bool diagTile = (tm == tn);

    // fragment base pointers: panel p = r16*8 + ks, fragment = p*512 + lane*8
    const unsigned short* baseA =
        G2 + (size_t)(tm * 8 + waveM * 4) * 8 * 512 + (size_t)lane * 8;
    const unsigned short* baseB =
        G2 + (size_t)(tn * 8 + waveN * 4) * 8 * 512 + (size_t)lane * 8;

    floatx4 acc[4][4];
#pragma unroll
    for (int mi = 0; mi < 4; ++mi)
#pragma unroll
        for (int ni = 0; ni < 4; ++ni)
            acc[mi][ni] = floatx4{-1.0f, -1.0f, -1.0f, -1.0f};  // folds (sim-1)

#pragma unroll
    for (int ks = 0; ks < 8; ++ks) {  // K = 8 * 32 = 256
        short8 af[4], bf[4];
#pragma unroll
        for (int mi = 0; mi < 4; ++mi)
            af[mi] = *(const short8*)(baseA + (size_t)((mi << 3) + ks) * 512);
#pragma unroll
        for (int ni = 0; ni < 4; ++ni)
            bf[ni] = *(const short8*)(baseB + (size_t)((ni << 3) + ks) * 512);
#pragma unroll
        for (int mi = 0; mi < 4; ++mi)
#pragma unroll
            for (int ni = 0; ni < 4; ++ni)
                acc[mi][ni] = __builtin_amdgcn_mfma_f32_16x16x32_bf16(
                    af[mi], bf[ni], acc[mi][ni], 0, 0, 0);
    }

    // ---- epilogue: shuffle-reduce, park in LDS, exactly-once stores ----
    int col_lab[4];
#pragma unroll
    for (int ni = 0; ni < 4; ++ni)
        col_lab[ni] = lab[(rowB0 + waveN * 64 + ni * 16 + cc) & labmask];

    float bse[4] = {}, bnu[4] = {}, bct[4] = {};

#pragma unroll
    for (int mi = 0; mi < 4; ++mi) {
#pragma unroll
        for (int r = 0; r < 4; ++r) {
            const int lrow = waveM * 64 + mi * 16 + cq * 4 + r;
            const int grow = rowA0 + lrow;
            const int rl = lab[grow & labmask];
            float se = 0.0f, nu = 0.0f, ct = 0.0f;
#pragma unroll
            for (int ni = 0; ni < 4; ++ni) {
                const int gcol = rowB0 + waveN * 64 + ni * 16 + cc;
                const float ls2 = acc[mi][ni][r] * K2_SCALE;  // base-2 logits
                const bool valid = (gcol != grow);
                const float e = valid ? exp2f(ls2) : 0.0f;
                const bool pos = valid && (col_lab[ni] == rl);
                const float nuv = pos ? ls2 : 0.0f;
                const float p = pos ? 1.0f : 0.0f;
                se += e; nu += nuv; ct += p;
                bse[ni] += e; bnu[ni] += nuv; bct[ni] += p;
            }
#pragma unroll
            for (int off = 1; off < 16; off <<= 1) {
                se += __shfl_xor(se, off, 64);
                nu += __shfl_xor(nu, off, 64);
                ct += __shfl_xor(ct, off, 64);
            }
            if (cc == 0) {
                red[0][waveN][lrow][0] = se;
                red[0][waveN][lrow][1] = nu;
                red[0][waveN][lrow][2] = ct;
            }
        }
    }

    if (!diagTile) {
#pragma unroll
        for (int ni = 0; ni < 4; ++ni) {
            float se = bse[ni], nu = bnu[ni], ct = bct[ni];
            se += __shfl_xor(se, 16, 64); nu += __shfl_xor(nu, 16, 64); ct += __shfl_xor(ct, 16, 64);
            se += __shfl_xor(se, 32, 64); nu += __shfl_xor(nu, 32, 64); ct += __shfl_xor(ct, 32, 64);
            if (cq == 0) {
                const int lcol = waveN * 64 + ni * 16 + cc;
                red[1][waveM][lcol][0] = se;
                red[1][waveM][lcol][1] = nu;
                red[1][waveM][lcol][2] = ct;
            }
        }
    }
    __syncthreads();

    // A-side partials -> slot tn, rows of tile tm (coalesced, exactly once)
    for (int v = tid; v < 384; v += 256) {
        const int c = v >> 7, r = v & 127;
        part[((size_t)(tn * 3 + c)) * M + rowA0 + r] =
            red[0][0][r][c] + red[0][1][r][c];
    }
    // B-side partials -> slot tm, rows of tile tn
    if (!diagTile) {
        for (int v = tid; v < 384; v += 256) {
            const int c = v >> 7, r = v & 127;
            part[((size_t)(tm * 3 + c)) * M + rowB0 + r] =
                red[1][0][r][c] + red[1][1][r][c];
        }
    }
}

// ---------------------------------------------------------------------------
// Kernel 4: per-row term = (nu*ln2)/ct - log(se), reducing over 64 slots.
// ---------------------------------------------------------------------------
__global__ void rowterm_kernel(const float* __restrict__ part,
                               float* __restrict__ terms, int M, int nslots) {
    const int row = blockIdx.x * 256 + threadIdx.x;
    if (row >= M) return;
    float se = 0.0f, nu = 0.0f, ct = 0.0f;
    for (int s = 0; s < nslots; ++s) {
        const float* p = part + (size_t)s * 3 * M;
        se += p[row];
        nu += p[M + row];
        ct += p[2 * M + row];
    }
    terms[row] = nu * LN2F / ct - logf(se);
}

// ---------------------------------------------------------------------------
// Kernel 5: final mean.
// ---------------------------------------------------------------------------
__global__ void reduce_kernel(const float* __restrict__ terms,
                              float* __restrict__ out, int M) {
    __shared__ float red[256];
    float s = 0.0f;
    for (int i = threadIdx.x; i < M; i += 256) s += terms[i];
    red[threadIdx.x] = s;
    __syncthreads();
    for (int k = 128; k; k >>= 1) {
        if (threadIdx.x < k) red[threadIdx.x] += red[threadIdx.x + k];
        __syncthreads();
    }
    if (threadIdx.x == 0) out[0] = -red[0] / (float)M;
}

extern "C" void kernel_launch(void* const* d_in, const int* in_sizes, int n_in,
                              void* d_out, int out_size, void* d_ws, size_t ws_size,
                              hipStream_t stream) {
    const float* features = (const float*)d_in[0];
    const int* labels_seg = (const int*)d_in[1];
    const int* labels_coords = (const int*)d_in[2];
    const int* crw = (const int*)d_in[3];
    const int* crh = (const int*)d_in[4];
    const int* crd = (const int*)d_in[5];
    float* out = (float*)d_out;

    const int N = in_sizes[2] / 3;          // 4096 patches
    const int M = in_sizes[0] / C_DIM;      // 8192 rows
    const int H = 128, W = 128, D = 128;
    const int nt = M / 128;                 // 64 row-blocks
    const int nblocks = nt * (nt + 1) / 2;  // 2080

    // workspace layout
    char* ws = (char*)d_ws;
    unsigned short* g2 = (unsigned short*)ws;                // M*256 bf16 tiled (4 MB)
    char* p1 = ws + (size_t)M * C_DIM * 2;
    int* lab = (int*)p1;                                     // N ints
    char* p2 = p1 + (size_t)N * 4;
    float* part = (float*)p2;                                // nt*3*M f32 (6.3 MB)
    char* p3 = p2 + (size_t)nt * 3 * M * 4;
    float* terms = (float*)p3;                               // M f32

    labels_kernel<<<(N + 255) / 256, 256, 0, stream>>>(
        labels_seg, labels_coords, crw, crh, crd, lab, N, H, W, D);

    norm_kernel<<<M / 4, 256, 0, stream>>>(features, g2);

    gram_kernel<<<nblocks, 256, 0, stream>>>(g2, lab, part, M, N - 1, nt);

    rowterm_kernel<<<(M + 255) / 256, 256, 0, stream>>>(part, terms, M, nt);

    reduce_kernel<<<1, 256, 0, stream>>>(terms, out, M);
}

// Round 7
// 189.842 us; speedup vs baseline: 1.5090x; 1.0875x over previous
//
#include <hip/hip_runtime.h>
#include <hip/hip_bf16.h>

typedef __attribute__((ext_vector_type(4))) float floatx4;

#define C_DIM 256
// (1/T) * log2(e) : logits scaled to base-2 so exp2f -> v_exp_f32 directly.
#define K2_SCALE 20.60992915f
#define LN2F 0.6931471805599453f

// ---------------------------------------------------------------------------
// Kernel 1: fused — L2-normalize rows of f (M x 256 fp32) -> fp8 e4m3 in
// MFMA-tiled layout g2, AND gather downsampled labels (first N global
// threads). Element (row,k) of g2 lives at byte
//   panel = (row>>4)*8 + (k>>5)
//   off   = panel*512 + ((k>>3)&3)*128 + (row&15)*8 + (k&7)
// so an MFMA fp8 fragment (16 rows x 32 k) is 64 lanes x 8 contiguous bytes
// -> one fully-coalesced 512B global_load_dwordx2 per fragment.
// One wave per row; lane l holds k = 4l..4l+3 -> one packed 4B store.
// ---------------------------------------------------------------------------
__global__ void norm_kernel(const float* __restrict__ f,
                            unsigned char* __restrict__ g2,
                            const int* __restrict__ seg,
                            const int* __restrict__ coords,
                            const int* __restrict__ crw,
                            const int* __restrict__ crh,
                            const int* __restrict__ crd,
                            int* __restrict__ lab,
                            int N, int H, int W, int D) {
    const int gid = blockIdx.x * blockDim.x + threadIdx.x;
    if (gid < N) {
        int c0 = coords[3 * gid + 0];
        int c1 = coords[3 * gid + 1];
        int c2 = coords[3 * gid + 2];
        int i0 = (c0 * H) / crw[0];
        int i1 = (c1 * W) / crh[0];
        int i2 = (c2 * D) / crd[0];
        lab[gid] = seg[(i0 * W + i1) * D + i2];
    }

    const int row = blockIdx.x * 4 + (threadIdx.x >> 6);
    const int l = threadIdx.x & 63;
    const float4 v = ((const float4*)(f + (size_t)row * C_DIM))[l];
    float ss = v.x * v.x + v.y * v.y + v.z * v.z + v.w * v.w;
#pragma unroll
    for (int off = 32; off; off >>= 1) ss += __shfl_xor(ss, off, 64);
    const float inv = 1.0f / sqrtf(ss);

    // pack 4 floats -> 4 fp8 e4m3 (OCP on gfx950) in one dword, bytes in
    // ascending k order.
    int packed = __builtin_amdgcn_cvt_pk_fp8_f32(v.x * inv, v.y * inv, 0, false);
    packed = __builtin_amdgcn_cvt_pk_fp8_f32(v.z * inv, v.w * inv, packed, true);

    // k = 4l: (k>>3)&3 = (l>>1)&3, k&7 = 4*(l&1)
    const size_t off2 = ((size_t)(row >> 4) * 8 + (l >> 3)) * 512 +
                        ((size_t)((l >> 1) & 3)) * 128 + (size_t)(row & 15) * 8 +
                        (l & 1) * 4;
    *(unsigned int*)(g2 + off2) = (unsigned int)packed;
}

// ---------------------------------------------------------------------------
// Kernel 2: symmetric Gram-tile kernel — barrier-free fp8 K-loop.
// Triangular 1D grid over 64 row-blocks of 128 (2080 blocks, R5 decode).
// 4 waves in 2x2; MFMA operands loaded DIRECTLY from tiled g2 (one coalesced
// 512B dwordx2 per fragment; g2 = 2 MB -> L2-resident on every XCD). No LDS,
// no barriers in the K-loop. Epilogue (R5/R6-proven): shuffle reduce -> park
// in 12KB LDS -> one barrier -> coalesced exactly-once stores into
// part[slot][3][M].
// ---------------------------------------------------------------------------
__global__ __launch_bounds__(256, 4) void
gram_kernel(const unsigned char* __restrict__ G2,
            const int* __restrict__ lab,
            float* __restrict__ part,
            int M, int labmask, int nt) {
    // ---- decode triangular block index (wave-uniform) ----
    const int b = blockIdx.x;
    float fnt = (float)nt;
    float disc = (2.0f * fnt + 1.0f) * (2.0f * fnt + 1.0f) - 8.0f * (float)b;
    int tm = (int)((2.0f * fnt + 1.0f - sqrtf(disc)) * 0.5f);
    if (tm < 0) tm = 0;
    if (tm > nt - 1) tm = nt - 1;
    while (tm > 0 && b < tm * nt - tm * (tm - 1) / 2) --tm;
    while (b >= (tm + 1) * nt - (tm + 1) * tm / 2) ++tm;
    const int tn = tm + (b - (tm * nt - tm * (tm - 1) / 2));

    __shared__ float red[2][2][128][3];   // 12.3 KB, epilogue only

    const int tid = threadIdx.x;
    const int lane = tid & 63;
    const int wave = tid >> 6;
    const int waveM = wave >> 1;
    const int waveN = wave & 1;
    const int cc = lane & 15;
    const int cq = lane >> 4;
    const int rowA0 = tm * 128;
    const int rowB0 = tn * 128;
    const bool diagTile = (tm == tn);

    // fragment base: panel p = row16*8 + ks, fragment = p*512 + lane*8 bytes
    const unsigned char* baseA =
        G2 + (size_t)(tm * 8 + waveM * 4) * 8 * 512 + (size_t)lane * 8;
    const unsigned char* baseB =
        G2 + (size_t)(tn * 8 + waveN * 4) * 8 * 512 + (size_t)lane * 8;

    floatx4 acc[4][4];
#pragma unroll
    for (int mi = 0; mi < 4; ++mi)
#pragma unroll
        for (int ni = 0; ni < 4; ++ni)
            acc[mi][ni] = floatx4{-1.0f, -1.0f, -1.0f, -1.0f};  // folds (sim-1)

#pragma unroll
    for (int ks = 0; ks < 8; ++ks) {  // K = 8 * 32 = 256
        long af[4], bf[4];
#pragma unroll
        for (int mi = 0; mi < 4; ++mi)
            af[mi] = *(const long*)(baseA + (size_t)(mi * 8 + ks) * 512);
#pragma unroll
        for (int ni = 0; ni < 4; ++ni)
            bf[ni] = *(const long*)(baseB + (size_t)(ni * 8 + ks) * 512);
#pragma unroll
        for (int mi = 0; mi < 4; ++mi)
#pragma unroll
            for (int ni = 0; ni < 4; ++ni)
                acc[mi][ni] = __builtin_amdgcn_mfma_f32_16x16x32_fp8_fp8(
                    af[mi], bf[ni], acc[mi][ni], 0, 0, 0);
    }

    // ---- epilogue: shuffle-reduce, park in LDS, exactly-once stores ----
    int col_lab[4];
#pragma unroll
    for (int ni = 0; ni < 4; ++ni)
        col_lab[ni] = lab[(rowB0 + waveN * 64 + ni * 16 + cc) & labmask];

    float bse[4] = {}, bnu[4] = {}, bct[4] = {};

#pragma unroll
    for (int mi = 0; mi < 4; ++mi) {
#pragma unroll
        for (int r = 0; r < 4; ++r) {
            const int lrow = waveM * 64 + mi * 16 + cq * 4 + r;
            const int grow = rowA0 + lrow;
            const int rl = lab[grow & labmask];
            float se = 0.0f, nu = 0.0f, ct = 0.0f;
#pragma unroll
            for (int ni = 0; ni < 4; ++ni) {
                const int gcol = rowB0 + waveN * 64 + ni * 16 + cc;
                const float ls2 = acc[mi][ni][r] * K2_SCALE;  // base-2 logits
                const bool valid = (gcol != grow);
                const float e = valid ? exp2f(ls2) : 0.0f;
                const bool pos = valid && (col_lab[ni] == rl);
                const float nuv = pos ? ls2 : 0.0f;
                const float p = pos ? 1.0f : 0.0f;
                se += e; nu += nuv; ct += p;
                bse[ni] += e; bnu[ni] += nuv; bct[ni] += p;
            }
#pragma unroll
            for (int off = 1; off < 16; off <<= 1) {
                se += __shfl_xor(se, off, 64);
                nu += __shfl_xor(nu, off, 64);
                ct += __shfl_xor(ct, off, 64);
            }
            if (cc == 0) {
                red[0][waveN][lrow][0] = se;
                red[0][waveN][lrow][1] = nu;
                red[0][waveN][lrow][2] = ct;
            }
        }
    }

    if (!diagTile) {
#pragma unroll
        for (int ni = 0; ni < 4; ++ni) {
            float se = bse[ni], nu = bnu[ni], ct = bct[ni];
            se += __shfl_xor(se, 16, 64); nu += __shfl_xor(nu, 16, 64); ct += __shfl_xor(ct, 16, 64);
            se += __shfl_xor(se, 32, 64); nu += __shfl_xor(nu, 32, 64); ct += __shfl_xor(ct, 32, 64);
            if (cq == 0) {
                const int lcol = waveN * 64 + ni * 16 + cc;
                red[1][waveM][lcol][0] = se;
                red[1][waveM][lcol][1] = nu;
                red[1][waveM][lcol][2] = ct;
            }
        }
    }
    __syncthreads();

    // A-side partials -> slot tn, rows of tile tm (coalesced, exactly once)
    for (int v = tid; v < 384; v += 256) {
        const int c = v >> 7, r = v & 127;
        part[((size_t)(tn * 3 + c)) * M + rowA0 + r] =
            red[0][0][r][c] + red[0][1][r][c];
    }
    // B-side partials -> slot tm, rows of tile tn
    if (!diagTile) {
        for (int v = tid; v < 384; v += 256) {
            const int c = v >> 7, r = v & 127;
            part[((size_t)(tm * 3 + c)) * M + rowB0 + r] =
                red[1][0][r][c] + red[1][1][r][c];
        }
    }
}

// ---------------------------------------------------------------------------
// Kernel 3: per-row term = (nu*ln2)/ct - log(se), reducing over 64 slots.
// ---------------------------------------------------------------------------
__global__ void rowterm_kernel(const float* __restrict__ part,
                               float* __restrict__ terms, int M, int nslots) {
    const int row = blockIdx.x * 256 + threadIdx.x;
    if (row >= M) return;
    float se = 0.0f, nu = 0.0f, ct = 0.0f;
    for (int s = 0; s < nslots; ++s) {
        const float* p = part + (size_t)s * 3 * M;
        se += p[row];
        nu += p[M + row];
        ct += p[2 * M + row];
    }
    terms[row] = nu * LN2F / ct - logf(se);
}

// ---------------------------------------------------------------------------
// Kernel 4: final mean.
// ---------------------------------------------------------------------------
__global__ void reduce_kernel(const float* __restrict__ terms,
                              float* __restrict__ out, int M) {
    __shared__ float red[256];
    float s = 0.0f;
    for (int i = threadIdx.x; i < M; i += 256) s += terms[i];
    red[threadIdx.x] = s;
    __syncthreads();
    for (int k = 128; k; k >>= 1) {
        if (threadIdx.x < k) red[threadIdx.x] += red[threadIdx.x + k];
        __syncthreads();
    }
    if (threadIdx.x == 0) out[0] = -red[0] / (float)M;
}

extern "C" void kernel_launch(void* const* d_in, const int* in_sizes, int n_in,
                              void* d_out, int out_size, void* d_ws, size_t ws_size,
                              hipStream_t stream) {
    const float* features = (const float*)d_in[0];
    const int* labels_seg = (const int*)d_in[1];
    const int* labels_coords = (const int*)d_in[2];
    const int* crw = (const int*)d_in[3];
    const int* crh = (const int*)d_in[4];
    const int* crd = (const int*)d_in[5];
    float* out = (float*)d_out;

    const int N = in_sizes[2] / 3;          // 4096 patches
    const int M = in_sizes[0] / C_DIM;      // 8192 rows
    const int H = 128, W = 128, D = 128;
    const int nt = M / 128;                 // 64 row-blocks
    const int nblocks = nt * (nt + 1) / 2;  // 2080

    // workspace layout
    char* ws = (char*)d_ws;
    unsigned char* g2 = (unsigned char*)ws;                  // M*256 fp8 tiled (2 MB)
    char* p1 = ws + (size_t)M * C_DIM;
    int* lab = (int*)p1;                                     // N ints
    char* p2 = p1 + (size_t)N * 4;
    float* part = (float*)p2;                                // nt*3*M f32 (6.3 MB)
    char* p3 = p2 + (size_t)nt * 3 * M * 4;
    float* terms = (float*)p3;                               // M f32

    norm_kernel<<<M / 4, 256, 0, stream>>>(features, g2, labels_seg,
                                           labels_coords, crw, crh, crd, lab,
                                           N, H, W, D);

    gram_kernel<<<nblocks, 256, 0, stream>>>(g2, lab, part, M, N - 1, nt);

    rowterm_kernel<<<(M + 255) / 256, 256, 0, stream>>>(part, terms, M, nt);

    reduce_kernel<<<1, 256, 0, stream>>>(terms, out, M);
}

// Round 8
// 142.800 us; speedup vs baseline: 2.0062x; 1.3294x over previous
//
#include <hip/hip_runtime.h>
#include <hip/hip_bf16.h>

typedef __attribute__((ext_vector_type(4))) float floatx4;

#define C_DIM 256
// (1/T) * log2(e) : logits scaled to base-2 so exp2f -> v_exp_f32 directly.
#define K2_SCALE 20.60992915f
#define LN2F 0.6931471805599453f

// ---------------------------------------------------------------------------
// Kernel 1: fused — L2-normalize rows of f (M x 256 fp32) -> fp8 e4m3 in
// MFMA-tiled layout g2, gather downsampled labels (first N global threads),
// and zero the finalize acc/done handshake. Element (row,k) of g2 at byte
//   panel = (row>>4)*8 + (k>>5)
//   off   = panel*512 + ((k>>3)&3)*128 + (row&15)*8 + (k&7)
// -> a 128-row block's panel is one CONTIGUOUS 32 KB blob (rows r16-groups
// tm*8..tm*8+7, each 8*512 B), ideal for global_load_lds staging.
// ---------------------------------------------------------------------------
__global__ void norm_kernel(const float* __restrict__ f,
                            unsigned char* __restrict__ g2,
                            const int* __restrict__ seg,
                            const int* __restrict__ coords,
                            const int* __restrict__ crw,
                            const int* __restrict__ crh,
                            const int* __restrict__ crd,
                            int* __restrict__ lab,
                            float* __restrict__ acc_done,
                            int N, int H, int W, int D) {
    const int gid = blockIdx.x * blockDim.x + threadIdx.x;
    if (gid == 0) {
        acc_done[0] = 0.0f;
        ((int*)acc_done)[1] = 0;
    }
    if (gid < N) {
        int c0 = coords[3 * gid + 0];
        int c1 = coords[3 * gid + 1];
        int c2 = coords[3 * gid + 2];
        int i0 = (c0 * H) / crw[0];
        int i1 = (c1 * W) / crh[0];
        int i2 = (c2 * D) / crd[0];
        lab[gid] = seg[(i0 * W + i1) * D + i2];
    }

    const int row = blockIdx.x * 4 + (threadIdx.x >> 6);
    const int l = threadIdx.x & 63;
    const float4 v = ((const float4*)(f + (size_t)row * C_DIM))[l];
    float ss = v.x * v.x + v.y * v.y + v.z * v.z + v.w * v.w;
#pragma unroll
    for (int off = 32; off; off >>= 1) ss += __shfl_xor(ss, off, 64);
    const float inv = 1.0f / sqrtf(ss);

    int packed = __builtin_amdgcn_cvt_pk_fp8_f32(v.x * inv, v.y * inv, 0, false);
    packed = __builtin_amdgcn_cvt_pk_fp8_f32(v.z * inv, v.w * inv, packed, true);

    const size_t off2 = ((size_t)(row >> 4) * 8 + (l >> 3)) * 512 +
                        ((size_t)((l >> 1) & 3)) * 128 + (size_t)(row & 15) * 8 +
                        (l & 1) * 4;
    *(unsigned int*)(g2 + off2) = (unsigned int)packed;
}

// ---------------------------------------------------------------------------
// Kernel 2: symmetric Gram-tile kernel — ONE-SHOT LDS staging.
// Triangular 1D grid over 64 row-blocks of 128 (2080 blocks).
// Because g2 is fragment-tiled, the A panel is bytes [tm*32768, +32768) and
// B is [tn*32768, +32768): stage both into LDS with global_load_lds width-16
// DMA (fire-and-forget, no VGPR round-trip), ONE barrier, then the entire
// K=256 MFMA loop runs from LDS ds_read_b64 (addr = lane*8 -> free 2-way).
// Per-block L2 read traffic halves vs direct loads (64 KB vs 128 KB).
// Epilogue (R5-R7 proven): shuffle reduce -> park in 12 KB LDS -> one
// barrier -> coalesced exactly-once stores into part[slot][3][M].
// LDS 64+12.3 KB -> 2 blocks/CU (8 waves resident).
// ---------------------------------------------------------------------------
__global__ __launch_bounds__(256, 2) void
gram_kernel(const unsigned char* __restrict__ G2,
            const int* __restrict__ lab,
            float* __restrict__ part,
            int M, int labmask, int nt) {
    // ---- decode triangular block index (wave-uniform) ----
    const int b = blockIdx.x;
    float fnt = (float)nt;
    float disc = (2.0f * fnt + 1.0f) * (2.0f * fnt + 1.0f) - 8.0f * (float)b;
    int tm = (int)((2.0f * fnt + 1.0f - sqrtf(disc)) * 0.5f);
    if (tm < 0) tm = 0;
    if (tm > nt - 1) tm = nt - 1;
    while (tm > 0 && b < tm * nt - tm * (tm - 1) / 2) --tm;
    while (b >= (tm + 1) * nt - (tm + 1) * tm / 2) ++tm;
    const int tn = tm + (b - (tm * nt - tm * (tm - 1) / 2));

    __shared__ unsigned char tiles[2][32768];   // 64 KB: A panel, B panel
    __shared__ float red[2][2][128][3];         // 12.3 KB, epilogue

    const int tid = threadIdx.x;
    const int lane = tid & 63;
    const int wave = tid >> 6;
    const int waveM = wave >> 1;
    const int waveN = wave & 1;
    const int cc = lane & 15;
    const int cq = lane >> 4;
    const int rowA0 = tm * 128;
    const int rowB0 = tn * 128;
    const bool diagTile = (tm == tn);

    // ---- one-shot DMA staging: 2 x 32 KB contiguous ----
    const unsigned char* gA = G2 + (size_t)tm * 32768;
    const unsigned char* gB = G2 + (size_t)tn * 32768;
#pragma unroll
    for (int i = 0; i < 8; ++i) {
        const int u = i * 256 + tid;            // 16B-chunk index, 0..2047
        const int ldsoff = (u & ~63) * 16;      // wave-uniform base
        __builtin_amdgcn_global_load_lds(
            (const __attribute__((address_space(1))) void*)(gA + (size_t)u * 16),
            (__attribute__((address_space(3))) void*)(&tiles[0][ldsoff]), 16, 0, 0);
        __builtin_amdgcn_global_load_lds(
            (const __attribute__((address_space(1))) void*)(gB + (size_t)u * 16),
            (__attribute__((address_space(3))) void*)(&tiles[1][ldsoff]), 16, 0, 0);
    }
    __syncthreads();

    floatx4 acc[4][4];
#pragma unroll
    for (int mi = 0; mi < 4; ++mi)
#pragma unroll
        for (int ni = 0; ni < 4; ++ni)
            acc[mi][ni] = floatx4{-1.0f, -1.0f, -1.0f, -1.0f};  // folds (sim-1)

    // ---- barrier-free K-loop from LDS: fragment = panel*512 + lane*8 ----
#pragma unroll
    for (int ks = 0; ks < 8; ++ks) {  // K = 8 * 32 = 256
        long af[4], bf[4];
#pragma unroll
        for (int mi = 0; mi < 4; ++mi)
            af[mi] = *(const long*)&tiles[0][(size_t)((waveM * 4 + mi) * 8 + ks) * 512 + lane * 8];
#pragma unroll
        for (int ni = 0; ni < 4; ++ni)
            bf[ni] = *(const long*)&tiles[1][(size_t)((waveN * 4 + ni) * 8 + ks) * 512 + lane * 8];
#pragma unroll
        for (int mi = 0; mi < 4; ++mi)
#pragma unroll
            for (int ni = 0; ni < 4; ++ni)
                acc[mi][ni] = __builtin_amdgcn_mfma_f32_16x16x32_fp8_fp8(
                    af[mi], bf[ni], acc[mi][ni], 0, 0, 0);
    }

    // ---- epilogue: shuffle-reduce, park in LDS, exactly-once stores ----
    int col_lab[4];
#pragma unroll
    for (int ni = 0; ni < 4; ++ni)
        col_lab[ni] = lab[(rowB0 + waveN * 64 + ni * 16 + cc) & labmask];

    float bse[4] = {}, bnu[4] = {}, bct[4] = {};

#pragma unroll
    for (int mi = 0; mi < 4; ++mi) {
#pragma unroll
        for (int r = 0; r < 4; ++r) {
            const int lrow = waveM * 64 + mi * 16 + cq * 4 + r;
            const int grow = rowA0 + lrow;
            const int rl = lab[grow & labmask];
            float se = 0.0f, nu = 0.0f, ct = 0.0f;
#pragma unroll
            for (int ni = 0; ni < 4; ++ni) {
                const int gcol = rowB0 + waveN * 64 + ni * 16 + cc;
                const float ls2 = acc[mi][ni][r] * K2_SCALE;  // base-2 logits
                const bool valid = (gcol != grow);
                const float e = valid ? exp2f(ls2) : 0.0f;
                const bool pos = valid && (col_lab[ni] == rl);
                const float nuv = pos ? ls2 : 0.0f;
                const float p = pos ? 1.0f : 0.0f;
                se += e; nu += nuv; ct += p;
                bse[ni] += e; bnu[ni] += nuv; bct[ni] += p;
            }
#pragma unroll
            for (int off = 1; off < 16; off <<= 1) {
                se += __shfl_xor(se, off, 64);
                nu += __shfl_xor(nu, off, 64);
                ct += __shfl_xor(ct, off, 64);
            }
            if (cc == 0) {
                red[0][waveN][lrow][0] = se;
                red[0][waveN][lrow][1] = nu;
                red[0][waveN][lrow][2] = ct;
            }
        }
    }

    if (!diagTile) {
#pragma unroll
        for (int ni = 0; ni < 4; ++ni) {
            float se = bse[ni], nu = bnu[ni], ct = bct[ni];
            se += __shfl_xor(se, 16, 64); nu += __shfl_xor(nu, 16, 64); ct += __shfl_xor(ct, 16, 64);
            se += __shfl_xor(se, 32, 64); nu += __shfl_xor(nu, 32, 64); ct += __shfl_xor(ct, 32, 64);
            if (cq == 0) {
                const int lcol = waveN * 64 + ni * 16 + cc;
                red[1][waveM][lcol][0] = se;
                red[1][waveM][lcol][1] = nu;
                red[1][waveM][lcol][2] = ct;
            }
        }
    }
    __syncthreads();

    // A-side partials -> slot tn, rows of tile tm (coalesced, exactly once)
    for (int v = tid; v < 384; v += 256) {
        const int c = v >> 7, r = v & 127;
        part[((size_t)(tn * 3 + c)) * M + rowA0 + r] =
            red[0][0][r][c] + red[0][1][r][c];
    }
    // B-side partials -> slot tm, rows of tile tn
    if (!diagTile) {
        for (int v = tid; v < 384; v += 256) {
            const int c = v >> 7, r = v & 127;
            part[((size_t)(tm * 3 + c)) * M + rowB0 + r] =
                red[1][0][r][c] + red[1][1][r][c];
        }
    }
}

// ---------------------------------------------------------------------------
// Kernel 3: fused finalize. Each of the 32 blocks handles 256 rows:
// reduce the 64 slots, term = (nu*ln2)/ct - log(se), block-reduce, then an
// acc/done handshake: atomicAdd partial into acc, fence, bump done; the last
// block reads the total and writes the loss. acc/done zeroed by norm_kernel.
// ---------------------------------------------------------------------------
__global__ void finalize_kernel(const float* __restrict__ part,
                                float* __restrict__ acc_done,
                                float* __restrict__ out, int M, int nslots,
                                int nblk) {
    const int row = blockIdx.x * 256 + threadIdx.x;
    float se = 0.0f, nu = 0.0f, ct = 0.0f;
    for (int s = 0; s < nslots; ++s) {
        const float* p = part + (size_t)s * 3 * M;
        se += p[row];
        nu += p[M + row];
        ct += p[2 * M + row];
    }
    float term = nu * LN2F / ct - logf(se);

    __shared__ float sred[256];
    sred[threadIdx.x] = term;
    __syncthreads();
    for (int k = 128; k; k >>= 1) {
        if (threadIdx.x < k) sred[threadIdx.x] += sred[threadIdx.x + k];
        __syncthreads();
    }
    if (threadIdx.x == 0) {
        atomicAdd(&acc_done[0], sred[0]);
        __threadfence();
        int old = atomicAdd((int*)&acc_done[1], 1);
        if (old == nblk - 1) {
            float total = atomicAdd(&acc_done[0], 0.0f);  // atomic read
            out[0] = -total / (float)M;
        }
    }
}

extern "C" void kernel_launch(void* const* d_in, const int* in_sizes, int n_in,
                              void* d_out, int out_size, void* d_ws, size_t ws_size,
                              hipStream_t stream) {
    const float* features = (const float*)d_in[0];
    const int* labels_seg = (const int*)d_in[1];
    const int* labels_coords = (const int*)d_in[2];
    const int* crw = (const int*)d_in[3];
    const int* crh = (const int*)d_in[4];
    const int* crd = (const int*)d_in[5];
    float* out = (float*)d_out;

    const int N = in_sizes[2] / 3;          // 4096 patches
    const int M = in_sizes[0] / C_DIM;      // 8192 rows
    const int H = 128, W = 128, D = 128;
    const int nt = M / 128;                 // 64 row-blocks
    const int nblocks = nt * (nt + 1) / 2;  // 2080

    // workspace layout
    char* ws = (char*)d_ws;
    unsigned char* g2 = (unsigned char*)ws;                  // M*256 fp8 tiled (2 MB)
    char* p1 = ws + (size_t)M * C_DIM;
    int* lab = (int*)p1;                                     // N ints
    char* p2 = p1 + (size_t)N * 4;
    float* part = (float*)p2;                                // nt*3*M f32 (6.3 MB)
    char* p3 = p2 + (size_t)nt * 3 * M * 4;
    float* acc_done = (float*)p3;                            // {acc, done}

    norm_kernel<<<M / 4, 256, 0, stream>>>(features, g2, labels_seg,
                                           labels_coords, crw, crh, crd, lab,
                                           acc_done, N, H, W, D);

    gram_kernel<<<nblocks, 256, 0, stream>>>(g2, lab, part, M, N - 1, nt);

    const int fblk = M / 256;               // 32
    finalize_kernel<<<fblk, 256, 0, stream>>>(part, acc_done, out, M, nt, fblk);
}

// Round 10
// 121.728 us; speedup vs baseline: 2.3534x; 1.1731x over previous
//
#include <hip/hip_runtime.h>
#include <hip/hip_bf16.h>

typedef __attribute__((ext_vector_type(4))) float floatx4;

#define C_DIM 256
// (1/T) * log2(e) : logits scaled to base-2 so exp2f -> v_exp_f32 directly.
#define K2_SCALE 20.60992915f
#define LN2F 0.6931471805599453f

// pack 4 fp32 -> 4 OCP fp8 e4m3 bytes in one dword (ascending order)
__device__ __forceinline__ unsigned int pack4fp8(float a, float b, float c, float d) {
    int w = __builtin_amdgcn_cvt_pk_fp8_f32(a, b, 0, false);
    w = __builtin_amdgcn_cvt_pk_fp8_f32(c, d, w, true);
    return (unsigned int)w;
}

// DPP-based add: x += x shuffled by CTRL (within a 16-lane row). VALU pipe,
// ~2-4 cyc, vs ds_swizzle ~30 cyc latency for __shfl_xor.
template <int CTRL>
__device__ __forceinline__ float dppadd(float x) {
    int y = __builtin_amdgcn_update_dpp(0, __builtin_bit_cast(int, x),
                                        CTRL, 0xf, 0xf, true);
    return x + __builtin_bit_cast(float, y);
}
// sum over the 16 lanes of a DPP row (result in all 16 lanes)
__device__ __forceinline__ float row16_sum(float x) {
    x = dppadd<0xB1>(x);    // quad_perm [1,0,3,2]  (xor 1)
    x = dppadd<0x4E>(x);    // quad_perm [2,3,0,1]  (xor 2)
    x = dppadd<0x124>(x);   // row_ror:4
    x = dppadd<0x128>(x);   // row_ror:8
    return x;
}

// ---------------------------------------------------------------------------
// Kernel 1: fused — labels gather (first N threads), zero acc/done, and
// L2-normalize 16 rows/block -> fp8 e4m3 in MFMA-fragment-tiled g2 with
// fully-coalesced 16 B/thread stores (two-phase via LDS).
// Tiled layout: element (row,k) at byte
//   (row>>4)*4096 + (k>>5)*512 + ((k>>3)&3)*128 + (row&15)*8 + (k&7)
// Writer thread t emits blob bytes [16t,16t+16): rows (2t)&15,(2t+1)&15,
// k-range (t>>5)*32 + ((t>>3)&3)*8 .. +8.   (index algebra verified)
// ---------------------------------------------------------------------------
__global__ void norm_kernel(const float* __restrict__ f,
                            unsigned char* __restrict__ g2,
                            const int* __restrict__ seg,
                            const int* __restrict__ coords,
                            const int* __restrict__ crw,
                            const int* __restrict__ crh,
                            const int* __restrict__ crd,
                            int* __restrict__ lab,
                            float* __restrict__ acc_done,
                            int N, int H, int W, int D) {
    __shared__ float nrm[16][264];
    const int tid = threadIdx.x;
    const int bid = blockIdx.x;
    const int gid = bid * 256 + tid;
    const int lane = tid & 63;
    const int wave = tid >> 6;

    if (gid == 0) {
        acc_done[0] = 0.0f;
        ((int*)acc_done)[1] = 0;
    }
    if (gid < N) {
        int c0 = coords[3 * gid + 0];
        int c1 = coords[3 * gid + 1];
        int c2 = coords[3 * gid + 2];
        int i0 = (c0 * H) / crw[0];
        int i1 = (c1 * W) / crh[0];
        int i2 = (c2 * D) / crd[0];
        lab[gid] = seg[(i0 * W + i1) * D + i2];
    }

    const int rbase = bid * 16;             // 512 blocks x 16 rows = M
#pragma unroll
    for (int q = 0; q < 4; ++q) {
        const int rl = wave * 4 + q;        // local row 0..15
        const float4 v = ((const float4*)(f + (size_t)(rbase + rl) * C_DIM))[lane];
        float ss = v.x * v.x + v.y * v.y + v.z * v.z + v.w * v.w;
#pragma unroll
        for (int off = 32; off; off >>= 1) ss += __shfl_xor(ss, off, 64);
        const float inv = 1.0f / sqrtf(ss);
        *(float4*)&nrm[rl][lane * 4] = float4{v.x * inv, v.y * inv, v.z * inv, v.w * inv};
    }
    __syncthreads();

    const int k0 = (tid >> 5) * 32 + ((tid >> 3) & 3) * 8;
    const float* ra = &nrm[(2 * tid) & 15][k0];
    const float* rb = &nrm[(2 * tid + 1) & 15][k0];
    uint4 o;
    o.x = pack4fp8(ra[0], ra[1], ra[2], ra[3]);
    o.y = pack4fp8(ra[4], ra[5], ra[6], ra[7]);
    o.z = pack4fp8(rb[0], rb[1], rb[2], rb[3]);
    o.w = pack4fp8(rb[4], rb[5], rb[6], rb[7]);
    *(uint4*)(g2 + (size_t)bid * 4096 + (size_t)tid * 16) = o;
}

// ---------------------------------------------------------------------------
// Kernel 2: chunked-persistent symmetric Gram kernel.
// 512 blocks; block b runs 4-5 CONTIGUOUS triangular tile indices
// (start = 4b+min(b,32)): A panel restaged only on tm change, diagonal
// tiles skip B staging (B aliases A). Per tile: one-shot global_load_lds
// width-16 staging (32 KB contiguous per panel), one barrier, barrier-free
// fp8 MFMA K-loop from LDS (ds_read_b64, addr=lane*8 -> free 2-way).
// Epilogue: DPP row16 reductions (VALU, no ds_swizzle chains) -> park in
// 6 KB LDS -> barrier -> exactly-once coalesced stores into part[slot][3][M]
// (A-side -> slot tn rows of tm; B-side -> slot tm rows of tn).
// LDS 71.7 KB -> 2 blocks/CU.
// ---------------------------------------------------------------------------
__global__ __launch_bounds__(256, 2) void
gram_kernel(const unsigned char* __restrict__ G2,
            const int* __restrict__ lab,
            float* __restrict__ part,
            int M, int labmask, int nt) {
    __shared__ unsigned char Abuf[32768];
    __shared__ unsigned char Bbuf[32768];
    __shared__ float red[2][2][128][3];

    const int tid = threadIdx.x;
    const int bid = blockIdx.x;
    const int lane = tid & 63;
    const int wave = tid >> 6;
    const int waveM = wave >> 1;
    const int waveN = wave & 1;
    const int cc = lane & 15;
    const int cq = lane >> 4;

    const int start = bid * 4 + (bid < 32 ? bid : 32);
    const int len = 4 + (bid < 32 ? 1 : 0);
    int tmPrev = -1;

    for (int s = 0; s < len; ++s) {
        const int idx = start + s;
        // decode triangular index (wave-uniform)
        float fnt = (float)nt;
        float disc = (2.0f * fnt + 1.0f) * (2.0f * fnt + 1.0f) - 8.0f * (float)idx;
        int tm = (int)((2.0f * fnt + 1.0f - sqrtf(disc)) * 0.5f);
        if (tm < 0) tm = 0;
        if (tm > nt - 1) tm = nt - 1;
        while (tm > 0 && idx < tm * nt - tm * (tm - 1) / 2) --tm;
        while (idx >= (tm + 1) * nt - (tm + 1) * tm / 2) ++tm;
        const int tn = tm + (idx - (tm * nt - tm * (tm - 1) / 2));

        const int rowA0 = tm * 128;
        const int rowB0 = tn * 128;
        const bool diagTile = (tm == tn);

        // ---- stage panels (32 KB contiguous each) via width-16 DMA ----
        if (tm != tmPrev) {
            const unsigned char* gA = G2 + (size_t)tm * 32768;
#pragma unroll
            for (int i = 0; i < 8; ++i) {
                const int u = i * 256 + tid;
                __builtin_amdgcn_global_load_lds(
                    (const __attribute__((address_space(1))) void*)(gA + (size_t)u * 16),
                    (__attribute__((address_space(3))) void*)(&Abuf[(u & ~63) * 16]),
                    16, 0, 0);
            }
            tmPrev = tm;
        }
        if (!diagTile) {
            const unsigned char* gB = G2 + (size_t)tn * 32768;
#pragma unroll
            for (int i = 0; i < 8; ++i) {
                const int u = i * 256 + tid;
                __builtin_amdgcn_global_load_lds(
                    (const __attribute__((address_space(1))) void*)(gB + (size_t)u * 16),
                    (__attribute__((address_space(3))) void*)(&Bbuf[(u & ~63) * 16]),
                    16, 0, 0);
            }
        }
        __syncthreads();

        const unsigned char* A = Abuf;
        const unsigned char* B = diagTile ? Abuf : Bbuf;

        floatx4 acc[4][4];
#pragma unroll
        for (int mi = 0; mi < 4; ++mi)
#pragma unroll
            for (int ni = 0; ni < 4; ++ni)
                acc[mi][ni] = floatx4{-1.0f, -1.0f, -1.0f, -1.0f};  // folds (sim-1)

#pragma unroll
        for (int ks = 0; ks < 8; ++ks) {  // K = 8 * 32 = 256
            long af[4], bf[4];
#pragma unroll
            for (int mi = 0; mi < 4; ++mi)
                af[mi] = *(const long*)&A[(size_t)((waveM * 4 + mi) * 8 + ks) * 512 + lane * 8];
#pragma unroll
            for (int ni = 0; ni < 4; ++ni)
                bf[ni] = *(const long*)&B[(size_t)((waveN * 4 + ni) * 8 + ks) * 512 + lane * 8];
#pragma unroll
            for (int mi = 0; mi < 4; ++mi)
#pragma unroll
                for (int ni = 0; ni < 4; ++ni)
                    acc[mi][ni] = __builtin_amdgcn_mfma_f32_16x16x32_fp8_fp8(
                        af[mi], bf[ni], acc[mi][ni], 0, 0, 0);
        }

        // ---- epilogue ----
        int col_lab[4];
#pragma unroll
        for (int ni = 0; ni < 4; ++ni)
            col_lab[ni] = lab[(rowB0 + waveN * 64 + ni * 16 + cc) & labmask];

        float bse[4] = {}, bnu[4] = {}, bct[4] = {};

#pragma unroll
        for (int mi = 0; mi < 4; ++mi) {
#pragma unroll
            for (int r = 0; r < 4; ++r) {
                const int lrow = waveM * 64 + mi * 16 + cq * 4 + r;
                const int grow = rowA0 + lrow;
                const int rl = lab[grow & labmask];
                float se = 0.0f, nu = 0.0f, ct = 0.0f;
#pragma unroll
                for (int ni = 0; ni < 4; ++ni) {
                    const int gcol = rowB0 + waveN * 64 + ni * 16 + cc;
                    const float ls2 = acc[mi][ni][r] * K2_SCALE;  // base-2 logits
                    const bool valid = (gcol != grow);
                    const float e = valid ? exp2f(ls2) : 0.0f;
                    const bool pos = valid && (col_lab[ni] == rl);
                    const float nuv = pos ? ls2 : 0.0f;
                    const float p = pos ? 1.0f : 0.0f;
                    se += e; nu += nuv; ct += p;
                    bse[ni] += e; bnu[ni] += nuv; bct[ni] += p;
                }
                // DPP reduction across the 16 cc lanes (VALU pipe)
                se = row16_sum(se);
                nu = row16_sum(nu);
                ct = row16_sum(ct);
                if (cc == 0) {
                    red[0][waveN][lrow][0] = se;
                    red[0][waveN][lrow][1] = nu;
                    red[0][waveN][lrow][2] = ct;
                }
            }
        }

        if (!diagTile) {
#pragma unroll
            for (int ni = 0; ni < 4; ++ni) {
                float se = bse[ni], nu = bnu[ni], ct = bct[ni];
                se += __shfl_xor(se, 16, 64); nu += __shfl_xor(nu, 16, 64); ct += __shfl_xor(ct, 16, 64);
                se += __shfl_xor(se, 32, 64); nu += __shfl_xor(nu, 32, 64); ct += __shfl_xor(ct, 32, 64);
                if (cq == 0) {
                    const int lcol = waveN * 64 + ni * 16 + cc;
                    red[1][waveM][lcol][0] = se;
                    red[1][waveM][lcol][1] = nu;
                    red[1][waveM][lcol][2] = ct;
                }
            }
        }
        __syncthreads();

        // A-side partials -> slot tn, rows of tile tm (exactly once)
        for (int v = tid; v < 384; v += 256) {
            const int c = v >> 7, r = v & 127;
            part[((size_t)(tn * 3 + c)) * M + rowA0 + r] =
                red[0][0][r][c] + red[0][1][r][c];
        }
        // B-side partials -> slot tm, rows of tile tn
        if (!diagTile) {
            for (int v = tid; v < 384; v += 256) {
                const int c = v >> 7, r = v & 127;
                part[((size_t)(tm * 3 + c)) * M + rowB0 + r] =
                    red[1][0][r][c] + red[1][1][r][c];
            }
        }
        __syncthreads();   // red[] / LDS safe for next tile's DMA
    }
}

// ---------------------------------------------------------------------------
// Kernel 3: parallel finalize. 128 blocks x 64 rows; wave g of 4 reduces
// slots [g*16, g*16+16) (coalesced 64-row loads), LDS combine, per-row
// term = (nu*ln2)/ct - log(se), wave-reduce, acc/done handshake; last
// block writes the loss. acc/done zeroed by norm_kernel.
// ---------------------------------------------------------------------------
__global__ void finalize_kernel(const float* __restrict__ part,
                                float* __restrict__ acc_done,
                                float* __restrict__ out, int M, int nslots,
                                int nblk) {
    __shared__ float fred[3][4][64];
    const int tid = threadIdx.x;
    const int g = tid >> 6;
    const int l = tid & 63;
    const int row = blockIdx.x * 64 + l;

    float se = 0.0f, nu = 0.0f, ct = 0.0f;
    const int s0 = g * (nslots / 4);
    for (int s = s0; s < s0 + nslots / 4; ++s) {
        const float* p = part + (size_t)s * 3 * M;
        se += p[row];
        nu += p[M + row];
        ct += p[2 * M + row];
    }
    fred[0][g][l] = se;
    fred[1][g][l] = nu;
    fred[2][g][l] = ct;
    __syncthreads();

    if (tid < 64) {
        se = fred[0][0][l] + fred[0][1][l] + fred[0][2][l] + fred[0][3][l];
        nu = fred[1][0][l] + fred[1][1][l] + fred[1][2][l] + fred[1][3][l];
        ct = fred[2][0][l] + fred[2][1][l] + fred[2][2][l] + fred[2][3][l];
        float term = nu * LN2F / ct - logf(se);
#pragma unroll
        for (int off = 32; off; off >>= 1) term += __shfl_xor(term, off, 64);
        if (l == 0) {
            atomicAdd(&acc_done[0], term);
            __threadfence();
            int old = atomicAdd((int*)&acc_done[1], 1);
            if (old == nblk - 1) {
                float total = atomicAdd(&acc_done[0], 0.0f);  // atomic read
                out[0] = -total / (float)M;
            }
        }
    }
}

extern "C" void kernel_launch(void* const* d_in, const int* in_sizes, int n_in,
                              void* d_out, int out_size, void* d_ws, size_t ws_size,
                              hipStream_t stream) {
    const float* features = (const float*)d_in[0];
    const int* labels_seg = (const int*)d_in[1];
    const int* labels_coords = (const int*)d_in[2];
    const int* crw = (const int*)d_in[3];
    const int* crh = (const int*)d_in[4];
    const int* crd = (const int*)d_in[5];
    float* out = (float*)d_out;

    const int N = in_sizes[2] / 3;          // 4096 patches
    const int M = in_sizes[0] / C_DIM;      // 8192 rows
    const int H = 128, W = 128, D = 128;
    const int nt = M / 128;                 // 64 row-blocks

    // workspace layout
    char* ws = (char*)d_ws;
    unsigned char* g2 = (unsigned char*)ws;                  // M*256 fp8 tiled (2 MB)
    char* p1 = ws + (size_t)M * C_DIM;
    int* lab = (int*)p1;                                     // N ints
    char* p2 = p1 + (size_t)N * 4;
    float* part = (float*)p2;                                // nt*3*M f32 (6.3 MB)
    char* p3 = p2 + (size_t)nt * 3 * M * 4;
    float* acc_done = (float*)p3;                            // {acc, done}

    norm_kernel<<<M / 16, 256, 0, stream>>>(features, g2, labels_seg,
                                            labels_coords, crw, crh, crd, lab,
                                            acc_done, N, H, W, D);

    gram_kernel<<<512, 256, 0, stream>>>(g2, lab, part, M, N - 1, nt);

    const int fblk = M / 64;                // 128
    finalize_kernel<<<fblk, 256, 0, stream>>>(part, acc_done, out, M, nt, fblk);
}